// Round 5
// baseline (182.258 us; speedup 1.0000x reference)
//
#include <hip/hip_runtime.h>

// LocalizationLoss: B=1048576, N=3, C=7. output (B,3,7) fp32, target (B,3,5) fp32.
// result = (5*(Sx+Sy+2*Swh) + 3*Sce - 0.5*Sbce)/(B*N) + 0.5   (scalar fp32)
//
// R1: per-block partials instead of one global atomic (77->59us).
// R2: wave-private LDS staging — neutral (62us) + scratch spills.
// R3: global_load_lds + dbuf pipeline — neutral (62us): vmcnt(0) before the
//     compute buffer's ds_reads drains the prefetch too; latency still exposed.
// R4: NO LDS data path. Each lane loads its own row directly (rows only need
//     4B alignment for dwordx4) into registers, ping-pong prefetch of row k+1
//     during row k's compute -> per-register vmcnt lets latency overlap VALU
//     within the wave. BCE folded for t in {0,1}.

#define ROWS 8
#define NBLK 512                       // 512*256 threads * 8 rows = B
#define GSTRIDE (NBLK * 256)           // 131072 threads
#define INV_BN (1.0f / 3145728.0f)

typedef float f4u __attribute__((ext_vector_type(4), aligned(4)));
typedef float f2u __attribute__((ext_vector_type(2), aligned(4)));

struct RowData {
  f4u o0, o1, o2, o3, o4; float o20;
  f4u t0, t1, t2; f2u t12; float t14;
};

__device__ __forceinline__ void load_row(const float* __restrict__ o,
                                         const float* __restrict__ t,
                                         RowData& R) {
  R.o0 = *(const f4u*)(o + 0);
  R.o1 = *(const f4u*)(o + 4);
  R.o2 = *(const f4u*)(o + 8);
  R.o3 = *(const f4u*)(o + 12);
  R.o4 = *(const f4u*)(o + 16);
  R.o20 = o[20];
  R.t0 = *(const f4u*)(t + 0);
  R.t1 = *(const f4u*)(t + 4);
  R.t2 = *(const f4u*)(t + 8);
  R.t12 = *(const f2u*)(t + 12);
  R.t14 = t[14];
}

__device__ __forceinline__ float compute_row(const RowData& R) {
  float o[21], t[15];
  o[0]=R.o0.x;  o[1]=R.o0.y;  o[2]=R.o0.z;  o[3]=R.o0.w;
  o[4]=R.o1.x;  o[5]=R.o1.y;  o[6]=R.o1.z;  o[7]=R.o1.w;
  o[8]=R.o2.x;  o[9]=R.o2.y;  o[10]=R.o2.z; o[11]=R.o2.w;
  o[12]=R.o3.x; o[13]=R.o3.y; o[14]=R.o3.z; o[15]=R.o3.w;
  o[16]=R.o4.x; o[17]=R.o4.y; o[18]=R.o4.z; o[19]=R.o4.w;
  o[20]=R.o20;
  t[0]=R.t0.x;  t[1]=R.t0.y;  t[2]=R.t0.z;  t[3]=R.t0.w;
  t[4]=R.t1.x;  t[5]=R.t1.y;  t[6]=R.t1.z;  t[7]=R.t1.w;
  t[8]=R.t2.x;  t[9]=R.t2.y;  t[10]=R.t2.z; t[11]=R.t2.w;
  t[12]=R.t12.x; t[13]=R.t12.y; t[14]=R.t14;

  float sbce = 0.f, sce = 0.f, sx = 0.f, sy = 0.f, swh = 0.f;
  float L[3][3];
  int cls[3];
  #pragma unroll
  for (int n = 0; n < 3; ++n) {
    const float p  = o[n * 7 + 0];
    const float tt = t[n * 5 + 0];
    const bool mk = (tt != 0.f);
    // presence is exactly 0.0 or 1.0 -> bce term = log(mk ? p : 1-p)
    sbce += __logf(mk ? p : 1.f - p);
    const float m = mk ? 1.f : 0.f;
    const float dx = o[n * 7 + 1] * m - t[n * 5 + 1];
    sx += dx * dx;
    const float dy = o[n * 7 + 2] * m - t[n * 5 + 2];
    sy += dy * dy;
    const float sp = mk ? __builtin_sqrtf(o[n * 7 + 3]) : 0.f;
    const float dw = sp - __builtin_sqrtf(t[n * 5 + 3]);
    swh += dw * dw;
    L[n][0] = o[n * 7 + 4] * m;
    L[n][1] = o[n * 7 + 5] * m;
    L[n][2] = o[n * 7 + 6] * m;
    cls[n] = (int)t[n * 5 + 4];
  }
  #pragma unroll
  for (int j = 0; j < 3; ++j) {
    // masked logits in [0,1] -> exp safe without max-subtraction
    const float e = __expf(L[0][j]) + __expf(L[1][j]) + __expf(L[2][j]);
    const float lse = __logf(e);
    const int idx = cls[j];
    const float sel = (idx == 0) ? L[0][j] : ((idx == 1) ? L[1][j] : L[2][j]);
    sce += lse - sel;
  }
  return 5.f * (sx + sy + 2.f * swh) + 3.f * sce - 0.5f * sbce;
}

__global__ __launch_bounds__(256) void loc_loss_kernel(
    const float* __restrict__ gout, const float* __restrict__ gtgt,
    float* __restrict__ ws) {
  const int tid = threadIdx.x;
  const size_t g = (size_t)blockIdx.x * 256 + tid;

  RowData R[2];
  load_row(gout + g * 21, gtgt + g * 15, R[0]);

  float acc = 0.f;
  #pragma unroll
  for (int k = 0; k < ROWS; ++k) {
    if (k + 1 < ROWS) {
      const size_t r = g + (size_t)(k + 1) * GSTRIDE;
      load_row(gout + r * 21, gtgt + r * 15, R[(k + 1) & 1]);
    }
    acc += compute_row(R[k & 1]);
  }

  // per-wave shuffle reduce -> one partial per wave (2048 total)
  #pragma unroll
  for (int off = 32; off > 0; off >>= 1) acc += __shfl_down(acc, off, 64);
  if ((tid & 63) == 0) ws[(size_t)blockIdx.x * 4 + (tid >> 6)] = acc;
}

__global__ __launch_bounds__(256) void loc_loss_finalize(
    const float* __restrict__ ws, float* __restrict__ out) {
  __shared__ float s_wave[4];
  const int tid = threadIdx.x;
  const float4* w4 = (const float4*)ws;  // 2048 partials = 512 float4
  float acc = 0.f;
  #pragma unroll
  for (int i = 0; i < 2; ++i) {
    float4 v = w4[tid + 256 * i];
    acc += (v.x + v.y) + (v.z + v.w);
  }
  #pragma unroll
  for (int off = 32; off > 0; off >>= 1) acc += __shfl_down(acc, off, 64);
  if ((tid & 63) == 0) s_wave[tid >> 6] = acc;
  __syncthreads();
  if (tid == 0) {
    out[0] = (s_wave[0] + s_wave[1] + s_wave[2] + s_wave[3]) * INV_BN + 0.5f;
  }
}

extern "C" void kernel_launch(void* const* d_in, const int* in_sizes, int n_in,
                              void* d_out, int out_size, void* d_ws, size_t ws_size,
                              hipStream_t stream) {
  const float* gout = (const float*)d_in[0];  // (B,3,7)
  const float* gtgt = (const float*)d_in[1];  // (B,3,5)
  float* ws = (float*)d_ws;                   // 2048 floats = 8 KB
  float* out = (float*)d_out;

  loc_loss_kernel<<<NBLK, 256, 0, stream>>>(gout, gtgt, ws);
  loc_loss_finalize<<<1, 256, 0, stream>>>(ws, out);
}

// Round 6
// 177.077 us; speedup vs baseline: 1.0293x; 1.0293x over previous
//
#include <hip/hip_runtime.h>

// LocalizationLoss: B=1048576, N=3, C=7. output (B,3,7) fp32, target (B,3,5) fp32.
// result = (5*(Sx+Sy+2*Swh) + 3*Sce - 0.5*Sbce)/(B*N) + 0.5   (scalar fp32)
//
// R1: per-block partials instead of one global atomic (77->59us).
// R2: wave-private LDS staging, no barriers — 62us. 16 waves/CU (LDS-capped).
// R3: global_load_lds + dbuf — 62us. 8 waves/CU.
// R4: register ping-pong, no LDS — 94us. VGPR=152, ~3.5 waves/CU.
//     Across rounds, demand BW tracks resident waves (~2.4 TB/s @16 w/CU,
//     ~1.6 @3.5) and is independent of HBM vs L3 source -> MLP-bound:
//     outstanding requests x waves is the limiter, never the pipes.
// R5: same staging style as R2/R3 but sized for 32 waves/CU: 32-row shots,
//     18KB LDS/block (8 blocks/CU), launch_bounds(256,8) to cap VGPRs<=64,
//     global_load_lds staging (no spills), no barriers. Compute on lanes 0-31
//     (VALU is ~15% busy; headroom is ample). Transcendentals cut 21->5/row:
//     bce 3logs->1 (product), wh 2sqrt->1 per anchor (expand the square),
//     ce 3 lse-logs->1 (product of the 3 softmax denominators).

#define NBLK 4096            // 4096 blocks x 4 waves x 2 shots x 32 rows = B
#define INV_BN (1.0f / 3145728.0f)

__device__ __forceinline__ void gl16(const float4* g, float4* l) {
  __builtin_amdgcn_global_load_lds(
      (const __attribute__((address_space(1))) unsigned int*)g,
      (__attribute__((address_space(3))) unsigned int*)l, 16, 0, 0);
}

// Stage 32 rows: o = 32*21 floats = 168 float4; t = 32*15 = 120 float4.
// Bases: row0 multiple of 32 -> 2688B / 1920B offsets, 16B-aligned.
__device__ __forceinline__ void stage32(const float* __restrict__ gout,
                                        const float* __restrict__ gtgt,
                                        size_t row0, int lane,
                                        float* so, float* st) {
  const float4* go4 = (const float4*)(gout + row0 * 21);
  const float4* gt4 = (const float4*)(gtgt + row0 * 15);
  float4* so4 = (float4*)so;
  float4* st4 = (float4*)st;
  gl16(go4 + lane, so4);
  gl16(go4 + 64 + lane, so4 + 64);
  if (lane < 40) gl16(go4 + 128 + lane, so4 + 128);
  gl16(gt4 + lane, st4);
  if (lane < 56) gl16(gt4 + 64 + lane, st4 + 64);
}

// Row math from LDS; active on lanes 0..31 (row = lane). Row strides 21/15
// are odd -> 32 active lanes hit 32 distinct banks, conflict-free.
__device__ __forceinline__ float compute_row(const float* so, const float* st,
                                             int lane) {
  const float* o = so + lane * 21;
  const float* t = st + lane * 15;
  float pbce = 1.f, sx = 0.f, sy = 0.f, swh = 0.f, sel = 0.f;
  float Lg[3][3];
  int cls[3];
  #pragma unroll
  for (int n = 0; n < 3; ++n) {
    const float tt = t[n * 5 + 0];
    const bool mk = (tt != 0.f);
    const float m = mk ? 1.f : 0.f;
    const float p = o[n * 7 + 0];
    pbce *= mk ? p : 1.f - p;               // fold 3 logs into 1
    const float dx = o[n * 7 + 1] * m - t[n * 5 + 1];
    sx += dx * dx;
    const float dy = o[n * 7 + 2] * m - t[n * 5 + 2];
    sy += dy * dy;
    const float o3 = o[n * 7 + 3], t3 = t[n * 5 + 3];
    // masked: (sqrt(o3)-sqrt(t3))^2 = o3 + t3 - 2*sqrt(o3*t3); unmasked: t3
    swh += t3 + (mk ? (o3 - 2.f * __builtin_sqrtf(o3 * t3)) : 0.f);
    Lg[n][0] = o[n * 7 + 4] * m;
    Lg[n][1] = o[n * 7 + 5] * m;
    Lg[n][2] = o[n * 7 + 6] * m;
    cls[n] = (int)t[n * 5 + 4];
  }
  float prodS = 1.f;
  #pragma unroll
  for (int j = 0; j < 3; ++j) {
    // masked logits in [0,1]; denominator S_j in [3, 3e] -> product <= ~550
    prodS *= __expf(Lg[0][j]) + __expf(Lg[1][j]) + __expf(Lg[2][j]);
    const int idx = cls[j];
    sel += (idx == 0) ? Lg[0][j] : ((idx == 1) ? Lg[1][j] : Lg[2][j]);
  }
  return 5.f * (sx + sy + 2.f * swh) + 3.f * (__logf(prodS) - sel)
         - 0.5f * __logf(pbce);
}

__global__ __launch_bounds__(256, 8) void loc_loss_kernel(
    const float* __restrict__ gout, const float* __restrict__ gtgt,
    float* __restrict__ ws) {
  // Wave-private single buffer: 32 rows * (21+15) floats = 4608 B per wave.
  // Block total 18432 B -> 8 blocks/CU -> 32 waves/CU.
  __shared__ float s_out[4][32 * 21];
  __shared__ float s_tgt[4][32 * 15];

  const int tid = threadIdx.x;
  const int w = tid >> 6;
  const int lane = tid & 63;
  const size_t wrow0 = (size_t)blockIdx.x * 256 + (size_t)w * 64;

  float acc = 0.f;
  #pragma unroll
  for (int s = 0; s < 2; ++s) {
    stage32(gout, gtgt, wrow0 + 32 * s, lane, s_out[w], s_tgt[w]);
    // compiler inserts s_waitcnt vmcnt(0) before the ds_reads (wave-local)
    if (lane < 32) acc += compute_row(s_out[w], s_tgt[w], lane);
  }

  // lanes 32-63 hold 0; full 64-lane reduce -> one partial per wave
  #pragma unroll
  for (int off = 32; off > 0; off >>= 1) acc += __shfl_down(acc, off, 64);
  if (lane == 0) ws[(size_t)blockIdx.x * 4 + w] = acc;
}

__global__ __launch_bounds__(256) void loc_loss_finalize(
    const float* __restrict__ ws, float* __restrict__ out) {
  __shared__ float s_wave[4];
  const int tid = threadIdx.x;
  const float4* w4 = (const float4*)ws;  // 16384 partials = 4096 float4
  float acc = 0.f;
  #pragma unroll
  for (int i = 0; i < 16; ++i) {
    float4 v = w4[tid + 256 * i];
    acc += (v.x + v.y) + (v.z + v.w);
  }
  #pragma unroll
  for (int off = 32; off > 0; off >>= 1) acc += __shfl_down(acc, off, 64);
  if ((tid & 63) == 0) s_wave[tid >> 6] = acc;
  __syncthreads();
  if (tid == 0) {
    out[0] = (s_wave[0] + s_wave[1] + s_wave[2] + s_wave[3]) * INV_BN + 0.5f;
  }
}

extern "C" void kernel_launch(void* const* d_in, const int* in_sizes, int n_in,
                              void* d_out, int out_size, void* d_ws, size_t ws_size,
                              hipStream_t stream) {
  const float* gout = (const float*)d_in[0];  // (B,3,7)
  const float* gtgt = (const float*)d_in[1];  // (B,3,5)
  float* ws = (float*)d_ws;                   // 16384 floats = 64 KB
  float* out = (float*)d_out;

  loc_loss_kernel<<<NBLK, 256, 0, stream>>>(gout, gtgt, ws);
  loc_loss_finalize<<<1, 256, 0, stream>>>(ws, out);
}

// Round 7
// 163.660 us; speedup vs baseline: 1.1136x; 1.0820x over previous
//
#include <hip/hip_runtime.h>

// LocalizationLoss: B=1048576, N=3, C=7. output (B,3,7) fp32, target (B,3,5) fp32.
// result = (5*(Sx+Sy+2*Swh) + 3*Sce - 0.5*Sbce)/(B*N) + 0.5   (scalar fp32)
//
// R1: per-block partials (77->59us).  R2: wave-private LDS, no barriers: 62us.
// R3: global_load_lds + 2-deep dbuf: 62us.  R4: register ping-pong: 94us
// (spills).  R5: 32-row shots, 8 blocks/CU, 20 waves/CU, VGPR=28: 58us.
// Demand BW pinned at ~2.6 TB/s (10.2 B/cyc/CU) across ALL structures while
// VALU<20%, conflicts=0, HBM-side 1.3 TB/s. Either a shared downstream
// ceiling (per-XCD fill path) or per-shot vmcnt(0) latency exposure.
// R6 (discriminator): 4 shots/wave on 2 rotating wave-private buffers —
// prefetch always issued one compute-phase ahead, so even a conservative
// vmcnt(0) drains latency hidden behind the PREVIOUS shot's compute — at
// 16 waves/CU (36.9KB LDS -> 4 blocks/CU), plus NT (aux=2, evict-first)
// on staging loads. If still ~58us -> platform demand ceiling -> ROOFLINE.

#define NBLK 2048            // 2048 blocks x 4 waves x 4 shots x 32 rows = B
#define INV_BN (1.0f / 3145728.0f)

__device__ __forceinline__ void gl16(const float4* g, float4* l) {
  // aux=2 -> NT (non-temporal, evict-first) on gfx950 CPol
  __builtin_amdgcn_global_load_lds(
      (const __attribute__((address_space(1))) unsigned int*)g,
      (__attribute__((address_space(3))) unsigned int*)l, 16, 0, 2);
}

// Stage 32 rows: o = 32*21 = 168 float4; t = 32*15 = 120 float4.
__device__ __forceinline__ void stage32(const float* __restrict__ gout,
                                        const float* __restrict__ gtgt,
                                        size_t row0, int lane,
                                        float* so, float* st) {
  const float4* go4 = (const float4*)(gout + row0 * 21);
  const float4* gt4 = (const float4*)(gtgt + row0 * 15);
  float4* so4 = (float4*)so;
  float4* st4 = (float4*)st;
  gl16(go4 + lane, so4);
  gl16(go4 + 64 + lane, so4 + 64);
  if (lane < 40) gl16(go4 + 128 + lane, so4 + 128);
  gl16(gt4 + lane, st4);
  if (lane < 56) gl16(gt4 + 64 + lane, st4 + 64);
}

// Row math from LDS; active on lanes 0..31 (row = lane). Strides 21/15 odd
// -> 32 lanes hit 32 distinct banks, conflict-free.
__device__ __forceinline__ float compute_row(const float* so, const float* st,
                                             int lane) {
  const float* o = so + lane * 21;
  const float* t = st + lane * 15;
  float pbce = 1.f, sx = 0.f, sy = 0.f, swh = 0.f, sel = 0.f;
  float Lg[3][3];
  int cls[3];
  #pragma unroll
  for (int n = 0; n < 3; ++n) {
    const float tt = t[n * 5 + 0];
    const bool mk = (tt != 0.f);
    const float m = mk ? 1.f : 0.f;
    const float p = o[n * 7 + 0];
    pbce *= mk ? p : 1.f - p;               // 3 logs -> 1
    const float dx = o[n * 7 + 1] * m - t[n * 5 + 1];
    sx += dx * dx;
    const float dy = o[n * 7 + 2] * m - t[n * 5 + 2];
    sy += dy * dy;
    const float o3 = o[n * 7 + 3], t3 = t[n * 5 + 3];
    swh += t3 + (mk ? (o3 - 2.f * __builtin_sqrtf(o3 * t3)) : 0.f);
    Lg[n][0] = o[n * 7 + 4] * m;
    Lg[n][1] = o[n * 7 + 5] * m;
    Lg[n][2] = o[n * 7 + 6] * m;
    cls[n] = (int)t[n * 5 + 4];
  }
  float prodS = 1.f;
  #pragma unroll
  for (int j = 0; j < 3; ++j) {
    prodS *= __expf(Lg[0][j]) + __expf(Lg[1][j]) + __expf(Lg[2][j]);
    const int idx = cls[j];
    sel += (idx == 0) ? Lg[0][j] : ((idx == 1) ? Lg[1][j] : Lg[2][j]);
  }
  return 5.f * (sx + sy + 2.f * swh) + 3.f * (__logf(prodS) - sel)
         - 0.5f * __logf(pbce);
}

__global__ __launch_bounds__(256, 8) void loc_loss_kernel(
    const float* __restrict__ gout, const float* __restrict__ gtgt,
    float* __restrict__ ws) {
  // 2 rotating wave-private buffers x 4 waves: 2*(2688+1920)*4 = 36864 B
  // -> 4 blocks/CU -> 16 waves/CU.
  __shared__ float sA_out[4][32 * 21];
  __shared__ float sA_tgt[4][32 * 15];
  __shared__ float sB_out[4][32 * 21];
  __shared__ float sB_tgt[4][32 * 15];

  const int tid = threadIdx.x;
  const int w = tid >> 6;
  const int lane = tid & 63;
  const size_t base = ((size_t)blockIdx.x * 4 + w) * 128;  // 4 shots x 32 rows

  float acc = 0.f;
  // Pipeline: A<-s0, B<-s1 | C(A), A<-s2 | C(B), B<-s3 | C(A) | C(B)
  stage32(gout, gtgt, base +  0, lane, sA_out[w], sA_tgt[w]);
  stage32(gout, gtgt, base + 32, lane, sB_out[w], sB_tgt[w]);
  if (lane < 32) acc += compute_row(sA_out[w], sA_tgt[w], lane);
  stage32(gout, gtgt, base + 64, lane, sA_out[w], sA_tgt[w]);
  if (lane < 32) acc += compute_row(sB_out[w], sB_tgt[w], lane);
  stage32(gout, gtgt, base + 96, lane, sB_out[w], sB_tgt[w]);
  if (lane < 32) acc += compute_row(sA_out[w], sA_tgt[w], lane);
  if (lane < 32) acc += compute_row(sB_out[w], sB_tgt[w], lane);

  // lanes 32-63 hold 0; full 64-lane reduce -> one partial per wave
  #pragma unroll
  for (int off = 32; off > 0; off >>= 1) acc += __shfl_down(acc, off, 64);
  if (lane == 0) ws[(size_t)blockIdx.x * 4 + w] = acc;
}

__global__ __launch_bounds__(256) void loc_loss_finalize(
    const float* __restrict__ ws, float* __restrict__ out) {
  __shared__ float s_wave[4];
  const int tid = threadIdx.x;
  const float4* w4 = (const float4*)ws;  // 8192 partials = 2048 float4
  float acc = 0.f;
  #pragma unroll
  for (int i = 0; i < 8; ++i) {
    float4 v = w4[tid + 256 * i];
    acc += (v.x + v.y) + (v.z + v.w);
  }
  #pragma unroll
  for (int off = 32; off > 0; off >>= 1) acc += __shfl_down(acc, off, 64);
  if ((tid & 63) == 0) s_wave[tid >> 6] = acc;
  __syncthreads();
  if (tid == 0) {
    out[0] = (s_wave[0] + s_wave[1] + s_wave[2] + s_wave[3]) * INV_BN + 0.5f;
  }
}

extern "C" void kernel_launch(void* const* d_in, const int* in_sizes, int n_in,
                              void* d_out, int out_size, void* d_ws, size_t ws_size,
                              hipStream_t stream) {
  const float* gout = (const float*)d_in[0];  // (B,3,7)
  const float* gtgt = (const float*)d_in[1];  // (B,3,5)
  float* ws = (float*)d_ws;                   // 8192 floats = 32 KB
  float* out = (float*)d_out;

  loc_loss_kernel<<<NBLK, 256, 0, stream>>>(gout, gtgt, ws);
  loc_loss_finalize<<<1, 256, 0, stream>>>(ws, out);
}